// Round 8
// baseline (310.022 us; speedup 1.0000x reference)
//
#include <hip/hip_runtime.h>
#include <hip/hip_bf16.h>
#include <stdint.h>

// ---------------------------------------------------------------------------
// Fused MHA: B=2,S=2048,D=1024,H=16,dk=64, fp32 in/out, NO softmax scale.
// bf16 MFMA + Markidis hi/lo splitting; flash attention, no-max softmax.
// R5: attnk 8-wave swapped-QK^T, in-register P via shuffles. 2-term V/out.
// R7: XCD-aware dispatch->work remap (T1) — verified: attnk FETCH 106->20MB.
// R8: act hi/lo split FUSED into gemm3t A-staging (fp32 A -> reg convert ->
//     swizzled ds_write). splitk now weights-only (4 tensors, ~34MB).
//     Same math bit-for-bit; removes ~100MB of split traffic + a kernel's
//     worth of launch/drain overhead.
// ---------------------------------------------------------------------------

using bf16 = __hip_bfloat16;
typedef __attribute__((ext_vector_type(8))) short v8s;   // 8 x bf16
typedef __attribute__((ext_vector_type(4))) float v4f;   // 4 x f32
typedef __attribute__((ext_vector_type(4))) unsigned int v4u;
union PW { v4u u; v8s s; };

#define NB_ ((size_t)4194304)  // B*S*D elements
#define ND_ ((size_t)1048576)  // D*D elements

__device__ __forceinline__ void async16(const void* g, void* l) {
  __builtin_amdgcn_global_load_lds(
      (const __attribute__((address_space(1))) unsigned int*)g,
      (__attribute__((address_space(3))) unsigned int*)l, 16, 0, 0);
}

__device__ __forceinline__ v4f mfma16(v8s a, v8s b, v4f c) {
  return __builtin_amdgcn_mfma_f32_16x16x32_bf16(a, b, c, 0, 0, 0);
}

__device__ __forceinline__ unsigned short bfbits(float x) {
  bf16 h = __float2bfloat16(x);
  unsigned short u;
  __builtin_memcpy(&u, &h, 2);
  return u;
}

// ---------------------------------------------------------------------------
// Split fp32 -> (hi, lo) bf16.  lo = bf16(x - float(hi)).  Weights only.
// ---------------------------------------------------------------------------
struct SplitArgs {
  const float4* src[4];
  ushort4* hi[4];
  ushort4* lo[4];
  int n4[4];
};

__global__ __launch_bounds__(256) void splitk(SplitArgs sa) {
  const int z = blockIdx.y;
  const float4* __restrict__ src = sa.src[z];
  ushort4* __restrict__ dh = sa.hi[z];
  ushort4* __restrict__ dl = sa.lo[z];
  const int n4 = sa.n4[z];
  const int stride = gridDim.x * blockDim.x;
  for (int i = blockIdx.x * blockDim.x + threadIdx.x; i < n4; i += stride) {
    const float4 x = src[i];
    float vals[4] = {x.x, x.y, x.z, x.w};
    unsigned short hs[4], ls[4];
#pragma unroll
    for (int j = 0; j < 4; ++j) {
      bf16 hb = __float2bfloat16(vals[j]);
      float rest = vals[j] - __bfloat162float(hb);
      hs[j] = bfbits(vals[j]);
      ls[j] = bfbits(rest);
    }
    ushort4 hv; hv.x = hs[0]; hv.y = hs[1]; hv.z = hs[2]; hv.w = hs[3];
    ushort4 lv; lv.x = ls[0]; lv.y = ls[1]; lv.z = ls[2]; lv.w = ls[3];
    dh[i] = hv;
    dl[i] = lv;
  }
}

// ---------------------------------------------------------------------------
// Split-precision GEMM: C = A * B^T + bias. terms=3: a0b0+a0b1+a1b0;
// terms=2: a0b0+a1b0. mode 0: hi/lo bf16 -> [B,H,S,dk]; mode 1: bf16 ->
// V^T [B,H,dk,S]; mode 2: fp32 -> [M,N].
// A source: if Af[z] != null, read fp32 A and hi/lo-convert in registers
// (bit-identical to splitk), ds_write into swizzled LDS. Else gload_lds
// from pre-split Ah/Al.
// XCD remap: xcd = blockIdx.x (gridDim.x=8); wy = bx*C + by%C, wx = by/C.
// ---------------------------------------------------------------------------
struct GemmArgs {
  const float* Af[3];
  const bf16* Ah[3];
  const bf16* Al[3];
  const bf16* Bh[3];
  const bf16* Bl[3];
  const float* bias[3];
  void* O0[3];
  void* O1[3];
  int mode[3];
  int terms[3];
};

template <int TM>
__global__ __launch_bounds__(256, TM == 128 ? 3 : 2) void gemm3t(GemmArgs ga) {
  constexpr int MFR = TM / 32;  // fragment rows per wave
  const int z = blockIdx.z;
  const float* __restrict__ Af = ga.Af[z];
  const bf16* __restrict__ Ah = ga.Ah[z];
  const bf16* __restrict__ Al = ga.Al[z];
  const bf16* __restrict__ Bh = ga.Bh[z];
  const bf16* __restrict__ Bl = ga.Bl[z];
  const float* __restrict__ bias = ga.bias[z];
  const int mode = ga.mode[z];
  const bool nt3 = (ga.terms[z] == 3);
  const bool f32a = (Af != nullptr);

  __shared__ alignas(16) bf16 lA0[TM * 32];
  __shared__ alignas(16) bf16 lA1[TM * 32];
  __shared__ alignas(16) bf16 lB0[128 * 32];
  __shared__ alignas(16) bf16 lB1[128 * 32];

  const int tid = threadIdx.x;
  const int lane = tid & 63;
  const int w = tid >> 6, wr = w >> 1, wc = w & 1;
  const int ln = lane & 15, g = lane >> 4;
  const int h4 = g * 4;

  // XCD-aware remap (T1): xcd == blockIdx.x under x-fastest round-robin.
  const int C = gridDim.y >> 3;  // M-tiles per XCD
  const int wy = blockIdx.x * C + (blockIdx.y % C);
  const int wx = blockIdx.y / C;
  const int m0 = wy * TM, n0 = wx * 128;

  v4f acc[MFR][4];
#pragma unroll
  for (int i = 0; i < MFR; ++i)
#pragma unroll
    for (int j = 0; j < 4; ++j)
#pragma unroll
      for (int r = 0; r < 4; ++r) acc[i][j][r] = 0.f;

  for (int k0 = 0; k0 < 1024; k0 += 32) {
    // ---- Stage A (TM x 32), swizzled chunk cs = (c ^ (row&3)).
    if (f32a) {
      // fp32 A -> hi/lo bf16 in regs -> ds_write_b128 (fused split).
#pragma unroll
      for (int p = 0; p < TM / 64; ++p) {
        const int idx = p * 256 + tid;
        const int row = idx >> 2, c = idx & 3;
        const int cs = (c ^ (row & 3)) * 8;
        const float* src = Af + (size_t)(m0 + row) * 1024 + k0 + cs;
        const float4 f0 = *(const float4*)(src);
        const float4 f1 = *(const float4*)(src + 4);
        const float vals[8] = {f0.x, f0.y, f0.z, f0.w, f1.x, f1.y, f1.z, f1.w};
        v8s hv, lv;
#pragma unroll
        for (int j = 0; j < 8; ++j) {
          bf16 hb = __float2bfloat16(vals[j]);
          hv[j] = (short)bfbits(vals[j]);
          lv[j] = (short)bfbits(vals[j] - __bfloat162float(hb));
        }
        *(v8s*)&lA0[idx * 8] = hv;
        *(v8s*)&lA1[idx * 8] = lv;
      }
    } else {
#pragma unroll
      for (int p = 0; p < TM / 64; ++p) {
        const int idx = p * 256 + tid;
        const int row = idx >> 2, c = idx & 3;
        const int cs = (c ^ (row & 3)) * 8;
        const size_t gA = (size_t)(m0 + row) * 1024 + k0 + cs;
        async16(Ah + gA, &lA0[idx * 8]);
        async16(Al + gA, &lA1[idx * 8]);
      }
    }
    // ---- Stage B (128 x 32).
#pragma unroll
    for (int p = 0; p < 2; ++p) {
      const int idx = p * 256 + tid;
      const int row = idx >> 2, c = idx & 3;
      const int cs = (c ^ (row & 3)) * 8;
      const size_t gB = (size_t)(n0 + row) * 1024 + k0 + cs;
      async16(Bh + gB, &lB0[idx * 8]);
      if (nt3) async16(Bl + gB, &lB1[idx * 8]);
    }
    __syncthreads();

    const char* pA0 = (const char*)lA0;
    const char* pA1 = (const char*)lA1;
    const char* pB0 = (const char*)lB0;
    const char* pB1 = (const char*)lB1;

    v8s a0[MFR], a1[MFR], b0[4], b1[4];
#pragma unroll
    for (int f = 0; f < MFR; ++f) {
      const int row = wr * (TM / 2) + f * 16 + ln;
      const int off = (row << 6) + ((g ^ (row & 3)) << 4);
      a0[f] = *(const v8s*)(pA0 + off);
      a1[f] = *(const v8s*)(pA1 + off);
    }
#pragma unroll
    for (int f = 0; f < 4; ++f) {
      const int row = wc * 64 + f * 16 + ln;
      const int off = (row << 6) + ((g ^ (row & 3)) << 4);
      b0[f] = *(const v8s*)(pB0 + off);
    }
    if (nt3) {
#pragma unroll
      for (int f = 0; f < 4; ++f) {
        const int row = wc * 64 + f * 16 + ln;
        const int off = (row << 6) + ((g ^ (row & 3)) << 4);
        b1[f] = *(const v8s*)(pB1 + off);
      }
    }
    __builtin_amdgcn_s_setprio(1);
#pragma unroll
    for (int i = 0; i < MFR; ++i)
#pragma unroll
      for (int j = 0; j < 4; ++j) {
        acc[i][j] = mfma16(a0[i], b0[j], acc[i][j]);
        acc[i][j] = mfma16(a1[i], b0[j], acc[i][j]);
      }
    if (nt3) {
#pragma unroll
      for (int i = 0; i < MFR; ++i)
#pragma unroll
        for (int j = 0; j < 4; ++j)
          acc[i][j] = mfma16(a0[i], b1[j], acc[i][j]);
    }
    __builtin_amdgcn_s_setprio(0);
    __syncthreads();
  }

  // Epilogue. C/D layout: col = lane&15, row = (lane>>4)*4 + reg.
#pragma unroll
  for (int i = 0; i < MFR; ++i)
#pragma unroll
    for (int j = 0; j < 4; ++j) {
      const int col = n0 + wc * 64 + j * 16 + ln;
      const float bb = bias[col];
#pragma unroll
      for (int r = 0; r < 4; ++r) {
        const int row = m0 + wr * (TM / 2) + i * 16 + h4 + r;
        const float vv = acc[i][j][r] + bb;
        if (mode == 2) {
          ((float*)ga.O0[z])[(size_t)row * 1024 + col] = vv;
        } else {
          const int b_ = row >> 11, s_ = row & 2047;
          const int hh = col >> 6, dd = col & 63;
          if (mode == 0) {
            const size_t o = (((size_t)(b_ * 16 + hh)) * 2048 + s_) * 64 + dd;
            bf16 hb = __float2bfloat16(vv);
            ((bf16*)ga.O0[z])[o] = hb;
            ((bf16*)ga.O1[z])[o] = __float2bfloat16(vv - __bfloat162float(hb));
          } else {  // mode 1: V^T
            const size_t o = (((size_t)(b_ * 16 + hh)) * 64 + dd) * 2048 + s_;
            ((bf16*)ga.O0[z])[o] = __float2bfloat16(vv);
          }
        }
      }
    }
}

// ---------------------------------------------------------------------------
// Flash attention, no-max softmax, swapped QK^T, in-register P.
// Block: 512 thr (8 waves), 128 q-rows (16/wave). KV tiles of 64,
// double-buffered + XOR-swizzled in LDS (48KB). sacc = mfma(K,Q):
// lane holds P[k=kvf*16+g*4+r][q=q0+ln]. P packed to bf16 pairs in
// registers, routed to PV A-fragments with computed-lane shuffles.
// XCD remap: xcd = bx%8; XCD owns 4 heads -> K/V L2-resident (verified:
// FETCH 106MB -> 20.5MB).
// ---------------------------------------------------------------------------
__global__ __launch_bounds__(512, 4) void attnk(
    const bf16* __restrict__ Qh, const bf16* __restrict__ Ql,
    const bf16* __restrict__ Kh, const bf16* __restrict__ Kl,
    const bf16* __restrict__ Vt,
    bf16* __restrict__ Oh, bf16* __restrict__ Ol) {
  __shared__ alignas(16) bf16 lKh[2][64 * 64];
  __shared__ alignas(16) bf16 lKl[2][64 * 64];
  __shared__ alignas(16) bf16 lVt[2][64 * 64];

  const int tid = threadIdx.x;
  const int lane = tid & 63, w = tid >> 6;      // 8 waves
  const int ln = lane & 15, g = lane >> 4;
  const int h8 = g * 8;

  // XCD-aware remap (T1): linear id = bx + 16*by -> xcd = bx%8.
  const int bx = blockIdx.x, by = blockIdx.y;
  const int bh = (bx & 7) + 8 * (by & 3);       // work head (b*16+h)
  const int qt = (by >> 2) * 2 + (bx >> 3);     // work q-tile [0,16)
  const int q0 = qt * 128 + w * 16;             // wave's 16 q-rows

  // Q fragments (B-operand of swapped QK^T): lane holds Q[q0+ln][.]
  v8s qh[2], ql[2];
  {
    const size_t rowg = (size_t)bh * 2048 + q0 + ln;
    qh[0] = *(const v8s*)&Qh[rowg * 64 + h8];
    qh[1] = *(const v8s*)&Qh[rowg * 64 + 32 + h8];
    ql[0] = *(const v8s*)&Ql[rowg * 64 + h8];
    ql[1] = *(const v8s*)&Ql[rowg * 64 + 32 + h8];
  }

  v4f O[4];        // [dkf]; col=d=dkf*16+ln, row=q_local=g*4+r
  float lpart = 0.f;
#pragma unroll
  for (int d = 0; d < 4; ++d)
#pragma unroll
    for (int r = 0; r < 4; ++r) O[d][r] = 0.f;

  // Stage: one 16B chunk per thread per buffer (512 thr = 64x8 chunks).
  const int srow = tid >> 3, sc = tid & 7;
  const int scs = (sc ^ (srow & 7)) * 8;
  auto stage = [&](int buf, int kv0) {
    const size_t gk = ((size_t)bh * 2048 + kv0 + srow) * 64 + scs;
    async16(Kh + gk, &lKh[buf][tid * 8]);
    async16(Kl + gk, &lKl[buf][tid * 8]);
    const size_t gv = ((size_t)bh * 64 + srow) * 2048 + kv0 + scs;
    async16(Vt + gv, &lVt[buf][tid * 8]);
  };

  stage(0, 0);
  __syncthreads();

  const int sA = ln + ((g & 1) << 5);
  const bool hiK = (g >> 1) != 0;

  for (int t = 0; t < 32; ++t) {
    const int cur = t & 1;
    if (t < 31) stage(cur ^ 1, (t + 1) * 64);  // prefetch next tile

    const char* kbh = (const char*)&lKh[cur][0];
    const char* kbl = (const char*)&lKl[cur][0];
    const char* vbb = (const char*)&lVt[cur][0];

    // S^T = K Q^T (3-term): sacc[kvf] value r = S[k=kvf*16+g*4+r][q=q0+ln]
    v4f sacc[4];
#pragma unroll
    for (int kvf = 0; kvf < 4; ++kvf)
#pragma unroll
      for (int r = 0; r < 4; ++r) sacc[kvf][r] = 0.f;

#pragma unroll
    for (int ks = 0; ks < 2; ++ks) {
      const int cbyte = (ks << 6) + (g << 4);
      v8s kh[4], kl[4];
#pragma unroll
      for (int kvf = 0; kvf < 4; ++kvf) {
        const int kr = kvf * 16 + ln;
        const int koff = (kr << 7) + (cbyte ^ ((kr & 7) << 4));
        kh[kvf] = *(const v8s*)(kbh + koff);
        kl[kvf] = *(const v8s*)(kbl + koff);
      }
      __builtin_amdgcn_s_setprio(1);
#pragma unroll
      for (int kvf = 0; kvf < 4; ++kvf) {
        sacc[kvf] = mfma16(kh[kvf], qh[ks], sacc[kvf]);
        sacc[kvf] = mfma16(kl[kvf], qh[ks], sacc[kvf]);
        sacc[kvf] = mfma16(kh[kvf], ql[ks], sacc[kvf]);
      }
      __builtin_amdgcn_s_setprio(0);
    }

    // P = exp(S); pack bf16 pairs (k even/odd) per lane; partial q-sums.
    unsigned wb[4][2];
#pragma unroll
    for (int kvf = 0; kvf < 4; ++kvf) {
      const float p0 = __expf(sacc[kvf][0]);
      const float p1 = __expf(sacc[kvf][1]);
      const float p2 = __expf(sacc[kvf][2]);
      const float p3 = __expf(sacc[kvf][3]);
      lpart += (p0 + p1) + (p2 + p3);
      wb[kvf][0] = (unsigned)bfbits(p0) | ((unsigned)bfbits(p1) << 16);
      wb[kvf][1] = (unsigned)bfbits(p2) | ((unsigned)bfbits(p3) << 16);
    }

    // O += P V: build PV A-fragment via computed-lane shuffles.
#pragma unroll
    for (int ks = 0; ks < 2; ++ks) {
      const unsigned a0 = __shfl(wb[2 * ks][0], sA, 64);
      const unsigned b0 = __shfl(wb[2 * ks + 1][0], sA, 64);
      const unsigned a1 = __shfl(wb[2 * ks][1], sA, 64);
      const unsigned b1 = __shfl(wb[2 * ks + 1][1], sA, 64);
      const unsigned a2 = __shfl(wb[2 * ks][0], sA + 16, 64);
      const unsigned b2 = __shfl(wb[2 * ks + 1][0], sA + 16, 64);
      const unsigned a3 = __shfl(wb[2 * ks][1], sA + 16, 64);
      const unsigned b3 = __shfl(wb[2 * ks + 1][1], sA + 16, 64);
      PW pw;
      pw.u = (v4u){hiK ? b0 : a0, hiK ? b1 : a1, hiK ? b2 : a2, hiK ? b3 : a3};
      const v8s pa = pw.s;

      const int cbyte = (ks << 6) + (g << 4);
      v8s vb[4];
#pragma unroll
      for (int dkf = 0; dkf < 4; ++dkf) {
        const int vr = dkf * 16 + ln;
        const int voff = (vr << 7) + (cbyte ^ ((vr & 7) << 4));
        vb[dkf] = *(const v8s*)(vbb + voff);
      }
      __builtin_amdgcn_s_setprio(1);
#pragma unroll
      for (int dkf = 0; dkf < 4; ++dkf)
        O[dkf] = mfma16(pa, vb[dkf], O[dkf]);
      __builtin_amdgcn_s_setprio(0);
    }
    __syncthreads();  // drains prefetch vmcnt + publishes buffers
  }

  // Row sums: lane holds partial for q=q0+ln over its 16 k's per tile;
  // the 4 g-group copies complete the sum.
  float s = lpart;
  s += __shfl_xor(s, 16, 64);
  s += __shfl_xor(s, 32, 64);
  const float sinv = 1.f / s;

  const int b_ = bh >> 4, hh = bh & 15;
#pragma unroll
  for (int r = 0; r < 4; ++r) {
    const float inv = __shfl(sinv, g * 4 + r, 64);  // sum for q=q0+g*4+r
    const int s_ = qt * 128 + w * 16 + g * 4 + r;
#pragma unroll
    for (int dkf = 0; dkf < 4; ++dkf) {
      const float o = O[dkf][r] * inv;
      const size_t off = ((size_t)b_ * 2048 + s_) * 1024 + hh * 64 + dkf * 16 + ln;
      bf16 hb = __float2bfloat16(o);
      Oh[off] = hb;
      Ol[off] = __float2bfloat16(o - __bfloat162float(hb));
    }
  }
}

// ---------------------------------------------------------------------------
extern "C" void kernel_launch(void* const* d_in, const int* in_sizes, int n_in,
                              void* d_out, int out_size, void* d_ws, size_t ws_size,
                              hipStream_t stream) {
  const float* q  = (const float*)d_in[0];
  const float* k  = (const float*)d_in[1];
  const float* v  = (const float*)d_in[2];
  const float* Wq = (const float*)d_in[3];
  const float* bq = (const float*)d_in[4];
  const float* Wk = (const float*)d_in[5];
  const float* bk = (const float*)d_in[6];
  const float* Wv = (const float*)d_in[7];
  const float* bv = (const float*)d_in[8];
  const float* Wo = (const float*)d_in[9];
  const float* bo = (const float*)d_in[10];

  const size_t NB = NB_, ND = ND_;
  bf16* P = (bf16*)d_ws;

  const bool fused = (ws_size >= (size_t)120 * 1024 * 1024);

  if (fused) {
    // Layout: 8ND weight splits + 5NB QKV tensors + 2NB attn-out = ~60 MB.
    bf16 *wqh = P, *wql = wqh + ND, *wkh = wql + ND, *wkl = wkh + ND;
    bf16 *wvh = wkl + ND, *wvl = wvh + ND, *woh = wvl + ND, *wol = woh + ND;
    bf16 *Qh = wol + ND, *Ql = Qh + NB, *Kh2 = Ql + NB, *Kl2 = Kh2 + NB, *Vt = Kl2 + NB;
    bf16 *Ah = Vt + NB, *Al = Ah + NB;

    SplitArgs sa{};
    const float* srcs[4] = {Wq, Wk, Wv, Wo};
    bf16* his[4] = {wqh, wkh, wvh, woh};
    bf16* los[4] = {wql, wkl, wvl, wol};
    for (int i = 0; i < 4; ++i) {
      sa.src[i] = (const float4*)srcs[i];
      sa.hi[i] = (ushort4*)his[i];
      sa.lo[i] = (ushort4*)los[i];
      sa.n4[i] = (int)(ND / 4);
    }
    splitk<<<dim3(512, 4), 256, 0, stream>>>(sa);

    GemmArgs ga{};
    ga.Af[0] = q; ga.Ah[0] = nullptr; ga.Al[0] = nullptr;
    ga.Bh[0] = wqh; ga.Bl[0] = wql;
    ga.bias[0] = bq; ga.O0[0] = Qh; ga.O1[0] = Ql; ga.mode[0] = 0; ga.terms[0] = 3;
    ga.Af[1] = k; ga.Ah[1] = nullptr; ga.Al[1] = nullptr;
    ga.Bh[1] = wkh; ga.Bl[1] = wkl;
    ga.bias[1] = bk; ga.O0[1] = Kh2; ga.O1[1] = Kl2; ga.mode[1] = 0; ga.terms[1] = 3;
    ga.Af[2] = v; ga.Ah[2] = nullptr; ga.Al[2] = nullptr;
    ga.Bh[2] = wvh; ga.Bl[2] = wvl;
    ga.bias[2] = bv; ga.O0[2] = Vt; ga.O1[2] = nullptr; ga.mode[2] = 1; ga.terms[2] = 2;
    gemm3t<128><<<dim3(8, 32, 3), 256, 0, stream>>>(ga);

    attnk<<<dim3(16, 32), 512, 0, stream>>>(Qh, Ql, Kh2, Kl2, Vt, Ah, Al);

    GemmArgs go{};
    go.Af[0] = nullptr; go.Ah[0] = Ah; go.Al[0] = Al;
    go.Bh[0] = woh; go.Bl[0] = wol;
    go.bias[0] = bo; go.O0[0] = d_out; go.O1[0] = nullptr; go.mode[0] = 2; go.terms[0] = 2;
    gemm3t<64><<<dim3(8, 64, 1), 256, 0, stream>>>(go);
  } else {
    // Tight layout (~46 MB): one weight-split buffer reused + QKV + attn-out.
    bf16 *wsh = P, *wsl = wsh + ND;
    bf16 *Qh = wsl + ND, *Ql = Qh + NB, *Kh2 = Ql + NB, *Kl2 = Kh2 + NB, *Vt = Kl2 + NB;
    bf16 *Ah = Vt + NB, *Al = Ah + NB;

    auto do_split1 = [&](const float* wsrc) {
      SplitArgs s{};
      s.src[0] = (const float4*)wsrc; s.hi[0] = (ushort4*)wsh; s.lo[0] = (ushort4*)wsl;
      s.n4[0] = (int)(ND / 4);
      splitk<<<dim3(512, 1), 256, 0, stream>>>(s);
    };
    auto do_gemm = [&](const float* af, const bf16* ah, const bf16* al,
                       const float* bias, void* o0, void* o1, int mode, int terms) {
      GemmArgs g{};
      g.Af[0] = af; g.Ah[0] = ah; g.Al[0] = al;
      g.Bh[0] = wsh; g.Bl[0] = wsl;
      g.bias[0] = bias; g.O0[0] = o0; g.O1[0] = o1; g.mode[0] = mode; g.terms[0] = terms;
      gemm3t<128><<<dim3(8, 32, 1), 256, 0, stream>>>(g);
    };

    do_split1(Wq); do_gemm(q, nullptr, nullptr, bq, Qh, Ql, 0, 3);
    do_split1(Wk); do_gemm(k, nullptr, nullptr, bk, Kh2, Kl2, 0, 3);
    do_split1(Wv); do_gemm(v, nullptr, nullptr, bv, Vt, nullptr, 1, 2);

    attnk<<<dim3(16, 32), 512, 0, stream>>>(Qh, Ql, Kh2, Kl2, Vt, Ah, Al);

    do_split1(Wo);
    GemmArgs g4{};
    g4.Af[0] = nullptr; g4.Ah[0] = Ah; g4.Al[0] = Al;
    g4.Bh[0] = wsh; g4.Bl[0] = wsl;
    g4.bias[0] = bo; g4.O0[0] = d_out; g4.O1[0] = nullptr; g4.mode[0] = 2; g4.terms[0] = 2;
    gemm3t<64><<<dim3(8, 64, 1), 256, 0, stream>>>(g4);
  }
}

// Round 11
// 289.210 us; speedup vs baseline: 1.0720x; 1.0720x over previous
//
#include <hip/hip_runtime.h>
#include <hip/hip_bf16.h>
#include <stdint.h>

// ---------------------------------------------------------------------------
// Fused MHA: B=2,S=2048,D=1024,H=16,dk=64, fp32 in/out, NO softmax scale.
// bf16 MFMA + Markidis hi/lo splitting; flash attention, no-max softmax.
// R5: attnk 8-wave swapped-QK^T. R7: XCD-aware remap (verified 5x FETCH cut).
// R8 REVERTED: fused A-split serialized staging latency (93->129us QKV).
// R9-R11: attnk PV via k-slot permutation pi(e)=32ks+16(e>>2)+4g+(e&3): P
//     stays lane-local (pa = direct repack of wb words, NO shuffles), V read
//     with pi-permuted offsets as 2x ds_read_b64. MFMA sums over k in any
//     order, so pi applied to BOTH operands is exact. -40% LDS-pipe/tile.
//     (R11 = identical resubmit; R9/R10 never ran: GPU acquisition timeouts.)
// ---------------------------------------------------------------------------

using bf16 = __hip_bfloat16;
typedef __attribute__((ext_vector_type(8))) short v8s;   // 8 x bf16
typedef __attribute__((ext_vector_type(4))) short v4s;   // 4 x bf16
typedef __attribute__((ext_vector_type(4))) float v4f;   // 4 x f32
typedef __attribute__((ext_vector_type(4))) unsigned int v4u;
union PW { v4u u; v8s s; };
union V8 { struct { v4s lo; v4s hi; } p; v8s v; };

#define NB_ ((size_t)4194304)  // B*S*D elements
#define ND_ ((size_t)1048576)  // D*D elements

__device__ __forceinline__ void async16(const void* g, void* l) {
  __builtin_amdgcn_global_load_lds(
      (const __attribute__((address_space(1))) unsigned int*)g,
      (__attribute__((address_space(3))) unsigned int*)l, 16, 0, 0);
}

__device__ __forceinline__ v4f mfma16(v8s a, v8s b, v4f c) {
  return __builtin_amdgcn_mfma_f32_16x16x32_bf16(a, b, c, 0, 0, 0);
}

__device__ __forceinline__ unsigned short bfbits(float x) {
  bf16 h = __float2bfloat16(x);
  unsigned short u;
  __builtin_memcpy(&u, &h, 2);
  return u;
}

// ---------------------------------------------------------------------------
// Split fp32 -> (hi, lo) bf16.  lo = bf16(x - float(hi)).
// ---------------------------------------------------------------------------
struct SplitArgs {
  const float4* src[7];
  ushort4* hi[7];
  ushort4* lo[7];
  int n4[7];
};

__global__ __launch_bounds__(256) void splitk(SplitArgs sa) {
  const int z = blockIdx.y;
  const float4* __restrict__ src = sa.src[z];
  ushort4* __restrict__ dh = sa.hi[z];
  ushort4* __restrict__ dl = sa.lo[z];
  const int n4 = sa.n4[z];
  const int stride = gridDim.x * blockDim.x;
  for (int i = blockIdx.x * blockDim.x + threadIdx.x; i < n4; i += stride) {
    const float4 x = src[i];
    float vals[4] = {x.x, x.y, x.z, x.w};
    unsigned short hs[4], ls[4];
#pragma unroll
    for (int j = 0; j < 4; ++j) {
      bf16 hb = __float2bfloat16(vals[j]);
      float rest = vals[j] - __bfloat162float(hb);
      hs[j] = bfbits(vals[j]);
      ls[j] = bfbits(rest);
    }
    ushort4 hv; hv.x = hs[0]; hv.y = hs[1]; hv.z = hs[2]; hv.w = hs[3];
    ushort4 lv; lv.x = ls[0]; lv.y = ls[1]; lv.z = ls[2]; lv.w = ls[3];
    dh[i] = hv;
    dl[i] = lv;
  }
}

// ---------------------------------------------------------------------------
// Split-precision GEMM: C = A * B^T + bias. terms=3: a0b0+a0b1+a1b0;
// terms=2: a0b0+a1b0. mode 0: hi/lo bf16 -> [B,H,S,dk]; mode 1: bf16 ->
// V^T [B,H,dk,S]; mode 2: fp32 -> [M,N].
// XCD remap: xcd = blockIdx.x (gridDim.x=8); wy = bx*C + by%C, wx = by/C.
// ---------------------------------------------------------------------------
struct GemmArgs {
  const bf16* Ah[3];
  const bf16* Al[3];
  const bf16* Bh[3];
  const bf16* Bl[3];
  const float* bias[3];
  void* O0[3];
  void* O1[3];
  int mode[3];
  int terms[3];
};

template <int TM>
__global__ __launch_bounds__(256, TM == 128 ? 3 : 2) void gemm3t(GemmArgs ga) {
  constexpr int MFR = TM / 32;  // fragment rows per wave
  const int z = blockIdx.z;
  const bf16* __restrict__ Ah = ga.Ah[z];
  const bf16* __restrict__ Al = ga.Al[z];
  const bf16* __restrict__ Bh = ga.Bh[z];
  const bf16* __restrict__ Bl = ga.Bl[z];
  const float* __restrict__ bias = ga.bias[z];
  const int mode = ga.mode[z];
  const bool nt3 = (ga.terms[z] == 3);

  __shared__ alignas(16) bf16 lA0[TM * 32];
  __shared__ alignas(16) bf16 lA1[TM * 32];
  __shared__ alignas(16) bf16 lB0[128 * 32];
  __shared__ alignas(16) bf16 lB1[128 * 32];

  const int tid = threadIdx.x;
  const int lane = tid & 63;
  const int w = tid >> 6, wr = w >> 1, wc = w & 1;
  const int ln = lane & 15, g = lane >> 4;
  const int h4 = g * 4;

  // XCD-aware remap (T1): xcd == blockIdx.x under x-fastest round-robin.
  const int C = gridDim.y >> 3;  // M-tiles per XCD
  const int wy = blockIdx.x * C + (blockIdx.y % C);
  const int wx = blockIdx.y / C;
  const int m0 = wy * TM, n0 = wx * 128;

  v4f acc[MFR][4];
#pragma unroll
  for (int i = 0; i < MFR; ++i)
#pragma unroll
    for (int j = 0; j < 4; ++j)
#pragma unroll
      for (int r = 0; r < 4; ++r) acc[i][j][r] = 0.f;

  for (int k0 = 0; k0 < 1024; k0 += 32) {
#pragma unroll
    for (int p = 0; p < TM / 64; ++p) {
      const int idx = p * 256 + tid;
      const int row = idx >> 2, c = idx & 3;
      const int cs = (c ^ (row & 3)) * 8;
      const size_t gA = (size_t)(m0 + row) * 1024 + k0 + cs;
      async16(Ah + gA, &lA0[idx * 8]);
      async16(Al + gA, &lA1[idx * 8]);
    }
#pragma unroll
    for (int p = 0; p < 2; ++p) {
      const int idx = p * 256 + tid;
      const int row = idx >> 2, c = idx & 3;
      const int cs = (c ^ (row & 3)) * 8;
      const size_t gB = (size_t)(n0 + row) * 1024 + k0 + cs;
      async16(Bh + gB, &lB0[idx * 8]);
      if (nt3) async16(Bl + gB, &lB1[idx * 8]);
    }
    __syncthreads();

    const char* pA0 = (const char*)lA0;
    const char* pA1 = (const char*)lA1;
    const char* pB0 = (const char*)lB0;
    const char* pB1 = (const char*)lB1;

    v8s a0[MFR], a1[MFR], b0[4], b1[4];
#pragma unroll
    for (int f = 0; f < MFR; ++f) {
      const int row = wr * (TM / 2) + f * 16 + ln;
      const int off = (row << 6) + ((g ^ (row & 3)) << 4);
      a0[f] = *(const v8s*)(pA0 + off);
      a1[f] = *(const v8s*)(pA1 + off);
    }
#pragma unroll
    for (int f = 0; f < 4; ++f) {
      const int row = wc * 64 + f * 16 + ln;
      const int off = (row << 6) + ((g ^ (row & 3)) << 4);
      b0[f] = *(const v8s*)(pB0 + off);
    }
    if (nt3) {
#pragma unroll
      for (int f = 0; f < 4; ++f) {
        const int row = wc * 64 + f * 16 + ln;
        const int off = (row << 6) + ((g ^ (row & 3)) << 4);
        b1[f] = *(const v8s*)(pB1 + off);
      }
    }
    __builtin_amdgcn_s_setprio(1);
#pragma unroll
    for (int i = 0; i < MFR; ++i)
#pragma unroll
      for (int j = 0; j < 4; ++j) {
        acc[i][j] = mfma16(a0[i], b0[j], acc[i][j]);
        acc[i][j] = mfma16(a1[i], b0[j], acc[i][j]);
      }
    if (nt3) {
#pragma unroll
      for (int i = 0; i < MFR; ++i)
#pragma unroll
        for (int j = 0; j < 4; ++j)
          acc[i][j] = mfma16(a0[i], b1[j], acc[i][j]);
    }
    __builtin_amdgcn_s_setprio(0);
    __syncthreads();
  }

  // Epilogue. C/D layout: col = lane&15, row = (lane>>4)*4 + reg.
#pragma unroll
  for (int i = 0; i < MFR; ++i)
#pragma unroll
    for (int j = 0; j < 4; ++j) {
      const int col = n0 + wc * 64 + j * 16 + ln;
      const float bb = bias[col];
#pragma unroll
      for (int r = 0; r < 4; ++r) {
        const int row = m0 + wr * (TM / 2) + i * 16 + h4 + r;
        const float vv = acc[i][j][r] + bb;
        if (mode == 2) {
          ((float*)ga.O0[z])[(size_t)row * 1024 + col] = vv;
        } else {
          const int b_ = row >> 11, s_ = row & 2047;
          const int hh = col >> 6, dd = col & 63;
          if (mode == 0) {
            const size_t o = (((size_t)(b_ * 16 + hh)) * 2048 + s_) * 64 + dd;
            bf16 hb = __float2bfloat16(vv);
            ((bf16*)ga.O0[z])[o] = hb;
            ((bf16*)ga.O1[z])[o] = __float2bfloat16(vv - __bfloat162float(hb));
          } else {  // mode 1: V^T
            const size_t o = (((size_t)(b_ * 16 + hh)) * 64 + dd) * 2048 + s_;
            ((bf16*)ga.O0[z])[o] = __float2bfloat16(vv);
          }
        }
      }
    }
}

// ---------------------------------------------------------------------------
// Flash attention, no-max softmax, swapped QK^T, in-register P.
// Block: 512 thr (8 waves), 128 q-rows (16/wave). KV tiles of 64,
// double-buffered + XOR-swizzled in LDS (48KB). sacc = mfma(K,Q):
// lane holds P[k=kvf*16+g*4+r][q=q0+ln].
// PV uses k-slot permutation pi(g*8+e) = 32ks + 16*(e>>2) + 4g + (e&3):
// pa = lane-local repack of wb words (no cross-lane ops); V fragment read
// with pi-permuted offsets (2x ds_read_b64 per dkf). Exact (sum reorder).
// XCD remap: xcd = bx%8 -> 4 heads/XCD, K/V L2-resident (verified).
// ---------------------------------------------------------------------------
__global__ __launch_bounds__(512, 4) void attnk(
    const bf16* __restrict__ Qh, const bf16* __restrict__ Ql,
    const bf16* __restrict__ Kh, const bf16* __restrict__ Kl,
    const bf16* __restrict__ Vt,
    bf16* __restrict__ Oh, bf16* __restrict__ Ol) {
  __shared__ alignas(16) bf16 lKh[2][64 * 64];
  __shared__ alignas(16) bf16 lKl[2][64 * 64];
  __shared__ alignas(16) bf16 lVt[2][64 * 64];

  const int tid = threadIdx.x;
  const int lane = tid & 63, w = tid >> 6;      // 8 waves
  const int ln = lane & 15, g = lane >> 4;
  const int h8 = g * 8;

  // XCD-aware remap (T1): linear id = bx + 16*by -> xcd = bx%8.
  const int bx = blockIdx.x, by = blockIdx.y;
  const int bh = (bx & 7) + 8 * (by & 3);       // work head (b*16+h)
  const int qt = (by >> 2) * 2 + (bx >> 3);     // work q-tile [0,16)
  const int q0 = qt * 128 + w * 16;             // wave's 16 q-rows

  // Q fragments (B-operand of swapped QK^T): lane holds Q[q0+ln][.]
  v8s qh[2], ql[2];
  {
    const size_t rowg = (size_t)bh * 2048 + q0 + ln;
    qh[0] = *(const v8s*)&Qh[rowg * 64 + h8];
    qh[1] = *(const v8s*)&Qh[rowg * 64 + 32 + h8];
    ql[0] = *(const v8s*)&Ql[rowg * 64 + h8];
    ql[1] = *(const v8s*)&Ql[rowg * 64 + 32 + h8];
  }

  v4f O[4];        // [dkf]; col=d=dkf*16+ln, row=q_local=g*4+r
  float lpart = 0.f;
#pragma unroll
  for (int d = 0; d < 4; ++d)
#pragma unroll
    for (int r = 0; r < 4; ++r) O[d][r] = 0.f;

  // Stage: one 16B chunk per thread per buffer (512 thr = 64x8 chunks).
  const int srow = tid >> 3, sc = tid & 7;
  const int scs = (sc ^ (srow & 7)) * 8;
  auto stage = [&](int buf, int kv0) {
    const size_t gk = ((size_t)bh * 2048 + kv0 + srow) * 64 + scs;
    async16(Kh + gk, &lKh[buf][tid * 8]);
    async16(Kl + gk, &lKl[buf][tid * 8]);
    const size_t gv = ((size_t)bh * 64 + srow) * 2048 + kv0 + scs;
    async16(Vt + gv, &lVt[buf][tid * 8]);
  };

  stage(0, 0);
  __syncthreads();

  for (int t = 0; t < 32; ++t) {
    const int cur = t & 1;
    if (t < 31) stage(cur ^ 1, (t + 1) * 64);  // prefetch next tile

    const char* kbh = (const char*)&lKh[cur][0];
    const char* kbl = (const char*)&lKl[cur][0];
    const char* vbb = (const char*)&lVt[cur][0];

    // S^T = K Q^T (3-term): sacc[kvf] value r = S[k=kvf*16+g*4+r][q=q0+ln]
    v4f sacc[4];
#pragma unroll
    for (int kvf = 0; kvf < 4; ++kvf)
#pragma unroll
      for (int r = 0; r < 4; ++r) sacc[kvf][r] = 0.f;

#pragma unroll
    for (int ks = 0; ks < 2; ++ks) {
      const int cbyte = (ks << 6) + (g << 4);
      v8s kh[4], kl[4];
#pragma unroll
      for (int kvf = 0; kvf < 4; ++kvf) {
        const int kr = kvf * 16 + ln;
        const int koff = (kr << 7) + (cbyte ^ ((kr & 7) << 4));
        kh[kvf] = *(const v8s*)(kbh + koff);
        kl[kvf] = *(const v8s*)(kbl + koff);
      }
      __builtin_amdgcn_s_setprio(1);
#pragma unroll
      for (int kvf = 0; kvf < 4; ++kvf) {
        sacc[kvf] = mfma16(kh[kvf], qh[ks], sacc[kvf]);
        sacc[kvf] = mfma16(kl[kvf], qh[ks], sacc[kvf]);
        sacc[kvf] = mfma16(kh[kvf], ql[ks], sacc[kvf]);
      }
      __builtin_amdgcn_s_setprio(0);
    }

    // P = exp(S); pack bf16 pairs per lane; partial q-sums.
    unsigned wb[4][2];
#pragma unroll
    for (int kvf = 0; kvf < 4; ++kvf) {
      const float p0 = __expf(sacc[kvf][0]);
      const float p1 = __expf(sacc[kvf][1]);
      const float p2 = __expf(sacc[kvf][2]);
      const float p3 = __expf(sacc[kvf][3]);
      lpart += (p0 + p1) + (p2 + p3);
      wb[kvf][0] = (unsigned)bfbits(p0) | ((unsigned)bfbits(p1) << 16);
      wb[kvf][1] = (unsigned)bfbits(p2) | ((unsigned)bfbits(p3) << 16);
    }

    // O += P V with permuted k-slots: pa element e holds P[q][pi(e)] where
    // pi(e) = 32ks + 16*(e>>2) + 4g + (e&3) — all lane-local. V fragment
    // reads V^T[d][pi(e)]: two 4-bf16 groups at bytes b0 and b0+32.
#pragma unroll
    for (int ks = 0; ks < 2; ++ks) {
      PW pw;
      pw.u = (v4u){wb[2 * ks][0], wb[2 * ks][1],
                   wb[2 * ks + 1][0], wb[2 * ks + 1][1]};
      const v8s pa = pw.s;
      const int b0 = (ks << 6) + (g << 3);
      const int b1 = b0 + 32;
      __builtin_amdgcn_s_setprio(1);
#pragma unroll
      for (int dkf = 0; dkf < 4; ++dkf) {
        const int vr = dkf * 16 + ln;
        const int xr = (vr & 7) << 4;
        const int off0 = (vr << 7) + ((b0 & ~15) ^ xr) + (b0 & 15);
        const int off1 = (vr << 7) + ((b1 & ~15) ^ xr) + (b1 & 15);
        V8 vv;
        vv.p.lo = *(const v4s*)(vbb + off0);
        vv.p.hi = *(const v4s*)(vbb + off1);
        O[dkf] = mfma16(pa, vv.v, O[dkf]);
      }
      __builtin_amdgcn_s_setprio(0);
    }
    __syncthreads();  // drains prefetch vmcnt + publishes buffers
  }

  // Row sums: lane holds partial for q=q0+ln over its 16 k's per tile;
  // the 4 g-group copies complete the sum.
  float s = lpart;
  s += __shfl_xor(s, 16, 64);
  s += __shfl_xor(s, 32, 64);
  const float sinv = 1.f / s;

  const int b_ = bh >> 4, hh = bh & 15;
#pragma unroll
  for (int r = 0; r < 4; ++r) {
    const float inv = __shfl(sinv, g * 4 + r, 64);  // sum for q=q0+g*4+r
    const int s_ = qt * 128 + w * 16 + g * 4 + r;
#pragma unroll
    for (int dkf = 0; dkf < 4; ++dkf) {
      const float o = O[dkf][r] * inv;
      const size_t off = ((size_t)b_ * 2048 + s_) * 1024 + hh * 64 + dkf * 16 + ln;
      bf16 hb = __float2bfloat16(o);
      Oh[off] = hb;
      Ol[off] = __float2bfloat16(o - __bfloat162float(hb));
    }
  }
}

// ---------------------------------------------------------------------------
extern "C" void kernel_launch(void* const* d_in, const int* in_sizes, int n_in,
                              void* d_out, int out_size, void* d_ws, size_t ws_size,
                              hipStream_t stream) {
  const float* q  = (const float*)d_in[0];
  const float* k  = (const float*)d_in[1];
  const float* v  = (const float*)d_in[2];
  const float* Wq = (const float*)d_in[3];
  const float* bq = (const float*)d_in[4];
  const float* Wk = (const float*)d_in[5];
  const float* bk = (const float*)d_in[6];
  const float* Wv = (const float*)d_in[7];
  const float* bv = (const float*)d_in[8];
  const float* Wo = (const float*)d_in[9];
  const float* bo = (const float*)d_in[10];

  const size_t NB = NB_, ND = ND_;
  bf16* P = (bf16*)d_ws;

  const bool fused = (ws_size >= (size_t)120 * 1024 * 1024);

  if (fused) {
    bf16 *qh = P, *ql = qh + NB, *kh = ql + NB, *kl = kh + NB, *vh = kl + NB, *vl = vh + NB;
    bf16 *wqh = vl + NB, *wql = wqh + ND, *wkh = wql + ND, *wkl = wkh + ND;
    bf16 *wvh = wkl + ND, *wvl = wvh + ND, *woh = wvl + ND, *wol = woh + ND;
    bf16 *Qh = wol + ND, *Ql = Qh + NB, *Kh2 = Ql + NB, *Kl2 = Kh2 + NB, *Vt = Kl2 + NB;
    bf16 *Ah = qh, *Al = ql;  // attention output reuses q-split buffers

    SplitArgs sa{};
    const float* srcs[7] = {q, k, v, Wq, Wk, Wv, Wo};
    bf16* his[7] = {qh, kh, vh, wqh, wkh, wvh, woh};
    bf16* los[7] = {ql, kl, vl, wql, wkl, wvl, wol};
    for (int i = 0; i < 7; ++i) {
      sa.src[i] = (const float4*)srcs[i];
      sa.hi[i] = (ushort4*)his[i];
      sa.lo[i] = (ushort4*)los[i];
      sa.n4[i] = (int)((i < 3 ? NB : ND) / 4);
    }
    splitk<<<dim3(512, 7), 256, 0, stream>>>(sa);

    GemmArgs ga{};
    ga.Ah[0] = qh; ga.Al[0] = ql; ga.Bh[0] = wqh; ga.Bl[0] = wql;
    ga.bias[0] = bq; ga.O0[0] = Qh; ga.O1[0] = Ql; ga.mode[0] = 0; ga.terms[0] = 3;
    ga.Ah[1] = kh; ga.Al[1] = kl; ga.Bh[1] = wkh; ga.Bl[1] = wkl;
    ga.bias[1] = bk; ga.O0[1] = Kh2; ga.O1[1] = Kl2; ga.mode[1] = 0; ga.terms[1] = 3;
    ga.Ah[2] = vh; ga.Al[2] = vl; ga.Bh[2] = wvh; ga.Bl[2] = wvl;
    ga.bias[2] = bv; ga.O0[2] = Vt; ga.O1[2] = nullptr; ga.mode[2] = 1; ga.terms[2] = 2;
    gemm3t<128><<<dim3(8, 32, 3), 256, 0, stream>>>(ga);

    attnk<<<dim3(16, 32), 512, 0, stream>>>(Qh, Ql, Kh2, Kl2, Vt, Ah, Al);

    GemmArgs go{};
    go.Ah[0] = Ah; go.Al[0] = Al; go.Bh[0] = woh; go.Bl[0] = wol;
    go.bias[0] = bo; go.O0[0] = d_out; go.O1[0] = nullptr; go.mode[0] = 2; go.terms[0] = 2;
    gemm3t<64><<<dim3(8, 64, 1), 256, 0, stream>>>(go);
  } else {
    bf16 *ash = P, *asl = ash + NB, *wsh = asl + NB, *wsl = wsh + ND;
    bf16 *Qh = wsl + ND, *Ql = Qh + NB, *Kh2 = Ql + NB, *Kl2 = Kh2 + NB, *Vt = Kl2 + NB;

    auto do_split2 = [&](const float* a, const float* wsrc) {
      SplitArgs s{};
      s.src[0] = (const float4*)a; s.hi[0] = (ushort4*)ash; s.lo[0] = (ushort4*)asl;
      s.n4[0] = (int)(NB / 4);
      s.src[1] = (const float4*)wsrc; s.hi[1] = (ushort4*)wsh; s.lo[1] = (ushort4*)wsl;
      s.n4[1] = (int)(ND / 4);
      splitk<<<dim3(512, 2), 256, 0, stream>>>(s);
    };
    auto do_gemm = [&](const float* bias, void* o0, void* o1, int mode, int terms) {
      GemmArgs g{};
      g.Ah[0] = ash; g.Al[0] = asl; g.Bh[0] = wsh; g.Bl[0] = wsl;
      g.bias[0] = bias; g.O0[0] = o0; g.O1[0] = o1; g.mode[0] = mode; g.terms[0] = terms;
      gemm3t<128><<<dim3(8, 32, 1), 256, 0, stream>>>(g);
    };

    do_split2(q, Wq); do_gemm(bq, Qh, Ql, 0, 3);
    do_split2(k, Wk); do_gemm(bk, Kh2, Kl2, 0, 3);
    do_split2(v, Wv); do_gemm(bv, Vt, nullptr, 1, 2);

    attnk<<<dim3(16, 32), 512, 0, stream>>>(Qh, Ql, Kh2, Kl2, Vt, ash, asl);

    SplitArgs s4{};
    s4.src[0] = (const float4*)Wo; s4.hi[0] = (ushort4*)wsh; s4.lo[0] = (ushort4*)wsl;
    s4.n4[0] = (int)(ND / 4);
    splitk<<<dim3(512, 1), 256, 0, stream>>>(s4);
    GemmArgs g4{};
    g4.Ah[0] = ash; g4.Al[0] = asl; g4.Bh[0] = wsh; g4.Bl[0] = wsl;
    g4.bias[0] = bo; g4.O0[0] = d_out; g4.O1[0] = nullptr; g4.mode[0] = 2; g4.terms[0] = 2;
    gemm3t<64><<<dim3(8, 64, 1), 256, 0, stream>>>(g4);
  }
}